// Round 4
// baseline (2967.964 us; speedup 1.0000x reference)
//
#include <hip/hip_runtime.h>

// VanillaRNN on MI355X — round 4: self-announcing h (value|tag in one u32).
// One MALL round trip per step: producer fires relaxed tagged stores and moves
// on (no drain, no flag, no fence); consumer polls its own data per 32-k chunk
// and computes the instant tags match. h prefetch overlaps the x-MFMAs.
// 16 clusters (16 batch rows) x 16 blocks (64 hidden outs), W' in VGPRs.

typedef __attribute__((ext_vector_type(8))) short short8;
typedef __attribute__((ext_vector_type(4))) float f32x4;
typedef __attribute__((ext_vector_type(4))) unsigned short u16x4;
typedef unsigned short u16;
typedef unsigned int u32;
typedef unsigned long long u64;

#define MF(A, B, C) (C) = __builtin_amdgcn_mfma_f32_16x16x32_bf16((A), (B), (C), 0, 0, 0)
#define ALOAD(p)    __hip_atomic_load((p), __ATOMIC_RELAXED, __HIP_MEMORY_SCOPE_AGENT)
#define ASTORE(p,v) __hip_atomic_store((p), (v), __ATOMIC_RELAXED, __HIP_MEMORY_SCOPE_AGENT)

// ---- workspace layout (bytes) ----
#define XPACK_OFF   0UL           // 16g * 512t * 8c * 64l * 16B = 67108864
#define WPACK_OFF   67108864UL    // 2560 frags * 1024B         = 2621440
#define WHOP_OFF    69730304UL    // 256 frags * 1024B          = 262144
#define HGLOB_OFF   69992448UL    // 16g * 2buf * 16384 u32     = 2097152
// total 72089600 bytes

__device__ __forceinline__ u16 f2bf(float f) {
  union { float f; unsigned u; } v; v.f = f;
  unsigned r = v.u + 0x7FFFu + ((v.u >> 16) & 1u);   // RNE
  return (u16)(r >> 16);
}

__device__ __forceinline__ float tanh_fast(float x) {
  float cx = fminf(10.f, fmaxf(-10.f, x));
  float e = __expf(2.f * cx);
  return (e - 1.f) / (e + 1.f);
}

__global__ __launch_bounds__(256) void zero_h_kernel(u32* __restrict__ h) {
  // cache-bypass stores so rnn_main's bypass loads cannot see stale tags
  ASTORE(h + (size_t)blockIdx.x * 256 + threadIdx.x, 0u);
}

// x [256b][512t][256k] fp32 -> xpack bf16 frags [g][t][c(8)][lane(64)][j(8)]
__global__ __launch_bounds__(256) void pack_x_kernel(const float* __restrict__ x, u16* __restrict__ xpack) {
  const int l = threadIdx.x & 63;
  const int rib = threadIdx.x >> 6;
  const long bt = (long)blockIdx.x * 4 + rib;   // b*512 + t
  const int b = (int)(bt >> 9);
  const int t = (int)(bt & 511);
  const f32x4 xv = *(const f32x4*)(x + bt * 256 + l * 4);
  const int k = l * 4;
  const int g = b >> 4;
  const int c = k >> 5;
  const int lt = ((k >> 3) & 3) * 16 + (b & 15);
  const int j = k & 7;
  u16x4 o;
  o[0] = f2bf(xv[0]); o[1] = f2bf(xv[1]); o[2] = f2bf(xv[2]); o[3] = f2bf(xv[3]);
  const long idx = ((((long)g * 512 + t) * 8 + c) * 64 + lt) * 8 + j;
  *(u16x4*)(xpack + idx) = o;
}

// W_hh[1024][1024], W_hx[1024][256] -> wpack frags [(s*4+w)*10+kc][nt][lane][8]
// W_ho[128][1024] -> whop frags [nt*32+c][lane][8]
__global__ __launch_bounds__(256) void pack_w_kernel(const float* __restrict__ Whh, const float* __restrict__ Whx,
                                                     const float* __restrict__ Who, u16* __restrict__ wpack,
                                                     u16* __restrict__ whop) {
  const int fid = blockIdx.x * 256 + threadIdx.x;
  const int l = fid & 63;
  const int frag = fid >> 6;
  const float* src;
  u16* dst;
  if (frag < 2560) {
    const int nt = frag & 3;
    const int kc = (frag >> 2) % 10;
    const int sw = frag / 40;          // s*4 + w
    const int w = sw & 3, s = sw >> 2;
    const int n = s * 64 + nt * 16 + (l & 15);
    if (kc < 8) src = Whh + n * 1024 + 32 * (8 * w + kc) + 8 * (l >> 4);
    else        src = Whx + n * 256  + 32 * (2 * w + kc - 8) + 8 * (l >> 4);
    dst = wpack + ((long)frag * 64 + l) * 8;
  } else if (frag < 2816) {
    const int f2 = frag - 2560;
    const int c = f2 & 31, nt = f2 >> 5;
    const int o = nt * 16 + (l & 15);
    src = Who + o * 1024 + 32 * c + 8 * (l >> 4);
    dst = whop + ((long)f2 * 64 + l) * 8;
  } else {
    return;
  }
  const f32x4 a = *(const f32x4*)src;
  const f32x4 b = *(const f32x4*)(src + 4);
  u16x4 o0, o1;
  o0[0] = f2bf(a[0]); o0[1] = f2bf(a[1]); o0[2] = f2bf(a[2]); o0[3] = f2bf(a[3]);
  o1[0] = f2bf(b[0]); o1[1] = f2bf(b[1]); o1[2] = f2bf(b[2]); o1[3] = f2bf(b[3]);
  *(u16x4*)dst = o0;
  *(u16x4*)(dst + 4) = o1;
}

extern "C" __global__ __launch_bounds__(256, 1) void rnn_main(
    const short8* __restrict__ xpack, const short8* __restrict__ wpack,
    const short8* __restrict__ whop, const float* __restrict__ bhx,
    const float* __restrict__ bho, u32* __restrict__ hglob,
    float* __restrict__ out) {
  __shared__ f32x4 red_lds[2][16 * 64];  // 32KB, double-buffered (1 barrier/step)
  extern __shared__ f32x4 red2[];        // dynamic pad (occupancy) + final scratch

  const int tid = threadIdx.x;
  const int w = tid >> 6;              // wave id = K-slice id = owned out-tile id
  const int l = tid & 63;
  const int lr = l & 15, lgp = l >> 4;
  const int bid = blockIdx.x;
  const int g = bid & 15;              // cluster (batch group)
  const int s = bid >> 4;              // 64-out slice within cluster

  const u64 MASK = 0x0000FFFF0000FFFFULL;

  // --- load W' fragments into registers, once (40 x short8 = 160 regs/lane) ---
  short8 wreg[10][4];
  {
    const short8* wp = wpack + (long)(s * 4 + w) * 10 * 4 * 64;
#pragma unroll
    for (int kc = 0; kc < 10; kc++)
#pragma unroll
      for (int nt = 0; nt < 4; nt++)
        wreg[kc][nt] = wp[(kc * 4 + nt) * 64 + l];
  }
  const float bias = bhx[s * 64 + w * 16 + lr];
  const int n = s * 64 + w * 16 + lr;            // out index this lane stores
  const int cst = n >> 5, ltb = ((n >> 3) & 3) * 16, jst = n & 7;

#pragma unroll 1
  for (int t = 0; t < 512; ++t) {
    // ---- prefetch tagged h (32 x u64 atomic loads), latency hidden under x-MFMAs
    u64 q[8][4];
    const u64* hq = (const u64*)(hglob + (size_t)(g * 2 + (t & 1)) * 16384);
    if (t > 0) {
#pragma unroll
      for (int i = 0; i < 8; i++) {
        const size_t qi = ((size_t)(w * 8 + i) * 64 + l) * 4;
#pragma unroll
        for (int r = 0; r < 4; r++) q[i][r] = ALOAD(hq + qi + r);
      }
    }

    // ---- x-part A-frags + 8 x-MFMAs (overlaps h prefetch latency)
    const short8* xp = xpack + (long)(g * 512 + t) * 8 * 64;
    short8 xa0 = xp[(2 * w + 0) * 64 + l];
    short8 xa1 = xp[(2 * w + 1) * 64 + l];

    f32x4 acc0 = {0.f, 0.f, 0.f, 0.f};
    f32x4 acc1 = acc0, acc2 = acc0, acc3 = acc0;

    MF(xa0, wreg[8][0], acc0); MF(xa0, wreg[8][1], acc1);
    MF(xa0, wreg[8][2], acc2); MF(xa0, wreg[8][3], acc3);
    MF(xa1, wreg[9][0], acc0); MF(xa1, wreg[9][1], acc1);
    MF(xa1, wreg[9][2], acc2); MF(xa1, wreg[9][3], acc3);

    if (t > 0) {
      const u64 tags2 = (u64)(u32)t | ((u64)(u32)t << 32);
#pragma unroll
      for (int i = 0; i < 8; i++) {
        const size_t qi = ((size_t)(w * 8 + i) * 64 + l) * 4;
        // verify chunk tags; retry only this chunk until its producer published
        for (;;) {
          u64 m = ((q[i][0] >> 16) ^ tags2) | ((q[i][1] >> 16) ^ tags2) |
                  ((q[i][2] >> 16) ^ tags2) | ((q[i][3] >> 16) ^ tags2);
          if (!__any((m & MASK) != 0)) break;
#pragma unroll
          for (int r = 0; r < 4; r++) q[i][r] = ALOAD(hq + qi + r);
        }
        // pack 8 tagged u32 -> short8 (strip tags)
        union { u32 d[4]; short8 v; } hu;
#pragma unroll
        for (int r = 0; r < 4; r++) {
          const u32 lo = (u32)q[i][r], hi = (u32)(q[i][r] >> 32);
          hu.d[r] = (lo & 0xFFFFu) | (hi << 16);
        }
        MF(hu.v, wreg[i][0], acc0);
        MF(hu.v, wreg[i][1], acc1);
        MF(hu.v, wreg[i][2], acc2);
        MF(hu.v, wreg[i][3], acc3);
      }
    }

    // ---- cross-wave reduction of K-partials (double-buffered LDS, 1 barrier)
    f32x4* red = red_lds[t & 1];
    red[(w * 4 + 0) * 64 + l] = acc0;
    red[(w * 4 + 1) * 64 + l] = acc1;
    red[(w * 4 + 2) * 64 + l] = acc2;
    red[(w * 4 + 3) * 64 + l] = acc3;
    __syncthreads();
    f32x4 ssum = red[(0 + w) * 64 + l] + red[(4 + w) * 64 + l] +
                 red[(8 + w) * 64 + l] + red[(12 + w) * 64 + l];

    // ---- epilogue: bias + tanh, publish tagged h_{t+1}; no fence, no drain
    u32* dst = hglob + (size_t)(g * 2 + ((t + 1) & 1)) * 16384;
    const u32 tg = (u32)(t + 1) << 16;
#pragma unroll
    for (int r = 0; r < 4; r++) {
      float hv = tanh_fast(ssum[r] + bias);
      ASTORE(dst + (size_t)(cst * 64 + ltb + 4 * lgp + r) * 8 + jst, (u32)f2bf(hv) | tg);
    }
  }

  // ---- final: logits + softmax, one block (s==0) per cluster ----
  if (s != 0) return;
  {
    const u64* hq = (const u64*)(hglob + (size_t)(g * 2 + 0) * 16384);  // h_512, tag 512
    const u64 tags2 = 512ULL | (512ULL << 32);
    f32x4 oa[8] = {};
#pragma unroll
    for (int i = 0; i < 8; i++) {
      const size_t qi = ((size_t)(w * 8 + i) * 64 + l) * 4;
      u64 q[4];
#pragma unroll
      for (int r = 0; r < 4; r++) q[r] = ALOAD(hq + qi + r);
      for (;;) {
        u64 m = ((q[0] >> 16) ^ tags2) | ((q[1] >> 16) ^ tags2) |
                ((q[2] >> 16) ^ tags2) | ((q[3] >> 16) ^ tags2);
        if (!__any((m & MASK) != 0)) break;
#pragma unroll
        for (int r = 0; r < 4; r++) q[r] = ALOAD(hq + qi + r);
      }
      union { u32 d[4]; short8 v; } hu;
#pragma unroll
      for (int r = 0; r < 4; r++) {
        const u32 lo = (u32)q[r], hi = (u32)(q[r] >> 32);
        hu.d[r] = (lo & 0xFFFFu) | (hi << 16);
      }
#pragma unroll
      for (int nt = 0; nt < 8; nt++)
        MF(hu.v, whop[(nt * 32 + w * 8 + i) * 64 + l], oa[nt]);
    }
#pragma unroll
    for (int nt = 0; nt < 8; nt++) red2[(w * 8 + nt) * 64 + l] = oa[nt];
  }
  __syncthreads();
#pragma unroll
  for (int qd = 0; qd < 2; qd++) {
    const int nt = 2 * w + qd;
    f32x4 lq = red2[(0 + nt) * 64 + l] + red2[(8 + nt) * 64 + l] +
               red2[(16 + nt) * 64 + l] + red2[(24 + nt) * 64 + l];
    const float bo = bho[nt * 16 + lr];
    lq[0] += bo; lq[1] += bo; lq[2] += bo; lq[3] += bo;
    red_lds[0][nt * 64 + l] = lq;
  }
  __syncthreads();
  if (w == 0) {
    const int b = l >> 2, qd = l & 3;  // 16 rows x 4 lane-groups (32 cols each)
    const float* redf = (const float*)red_lds[0];
    float vv[32];
    float mx = -3.0e38f;
#pragma unroll
    for (int jj = 0; jj < 32; jj++) {
      const int o = qd * 32 + jj;
      const int nt = o >> 4, m = o & 15;
      const float lv = redf[(nt * 64 + (b >> 2) * 16 + m) * 4 + (b & 3)];
      vv[jj] = lv;
      mx = fmaxf(mx, lv);
    }
    mx = fmaxf(mx, __shfl_xor(mx, 1));
    mx = fmaxf(mx, __shfl_xor(mx, 2));
    float se = 0.f;
#pragma unroll
    for (int jj = 0; jj < 32; jj++) { float e = __expf(vv[jj] - mx); vv[jj] = e; se += e; }
    se += __shfl_xor(se, 1);
    se += __shfl_xor(se, 2);
    const float inv = 1.f / se;
#pragma unroll
    for (int jj = 0; jj < 32; jj++)
      out[(g * 16 + b) * 128 + qd * 32 + jj] = vv[jj] * inv;
  }
}

extern "C" void kernel_launch(void* const* d_in, const int* in_sizes, int n_in,
                              void* d_out, int out_size, void* d_ws, size_t ws_size,
                              hipStream_t stream) {
  const float* x   = (const float*)d_in[0];
  const float* Whx = (const float*)d_in[1];
  const float* bhx = (const float*)d_in[2];
  const float* Whh = (const float*)d_in[3];
  const float* Who = (const float*)d_in[4];
  const float* bho = (const float*)d_in[5];
  float* out = (float*)d_out;
  char* ws = (char*)d_ws;

  u16* xpack = (u16*)(ws + XPACK_OFF);
  u16* wpack = (u16*)(ws + WPACK_OFF);
  u16* whop  = (u16*)(ws + WHOP_OFF);
  u32* hglob = (u32*)(ws + HGLOB_OFF);

  zero_h_kernel<<<2048, 256, 0, stream>>>(hglob);   // 2MB of tags -> 0 every call
  pack_x_kernel<<<32768, 256, 0, stream>>>(x, xpack);
  pack_w_kernel<<<704, 256, 0, stream>>>(Whh, Whx, Who, wpack, whop);

  // LDS: static 32KB + dynamic 56KB = 88KB -> exactly 1 block/CU (spin-sync safe,
  // 256 blocks on 256 CUs). Fall back keeps correctness (all blocks still resident).
  size_t dynsz = 57344;
  if (hipFuncSetAttribute((const void*)rnn_main,
                          hipFuncAttributeMaxDynamicSharedMemorySize, 57344) != hipSuccess)
    dynsz = 32768;

  rnn_main<<<256, 256, dynsz, stream>>>((const short8*)xpack, (const short8*)wpack,
                                        (const short8*)whop, bhx, bho, hglob, out);
}

// Round 5
// 1966.363 us; speedup vs baseline: 1.5094x; 1.5094x over previous
//
#include <hip/hip_runtime.h>

// VanillaRNN on MI355X — round 5: round-3 skeleton (flag-based, best measured)
// + xa software pipeline (prefetch t+1 x-frags during step t; removes the
//   ~0.9us HBM-latency prefix from the serial chain)
// + per-wave flag publish (count to 64; drops the pre-flag barrier) with
//   double-buffered LDS reduction.
// 16 clusters (16 batch rows) x 16 blocks (64 hidden outs), W' in VGPRs.
// h handoff: MALL-coherent relaxed agent atomics; NO agent fences in loop.

typedef __attribute__((ext_vector_type(8))) short short8;
typedef __attribute__((ext_vector_type(4))) float f32x4;
typedef __attribute__((ext_vector_type(4))) unsigned short u16x4;
typedef unsigned short u16;
typedef unsigned int u32;
typedef unsigned long long u64;

#define MF(A, B, C) (C) = __builtin_amdgcn_mfma_f32_16x16x32_bf16((A), (B), (C), 0, 0, 0)
#define ALOAD(p)    __hip_atomic_load((p), __ATOMIC_RELAXED, __HIP_MEMORY_SCOPE_AGENT)
#define ASTORE(p,v) __hip_atomic_store((p), (v), __ATOMIC_RELAXED, __HIP_MEMORY_SCOPE_AGENT)

// ---- workspace layout (bytes) ----
#define XPACK_OFF   0UL           // 16g * 512t * 8c * 64l * 16B = 67108864
#define WPACK_OFF   67108864UL    // 2560 frags * 1024B         = 2621440
#define WHOP_OFF    69730304UL    // 256 frags * 1024B          = 262144
#define HGLOB_OFF   69992448UL    // 16g * 2buf * 32KB          = 1048576
#define FLAGS_OFF   71041024UL    // 512*16 * 128B              = 1048576
// total 72089600 bytes

__device__ __forceinline__ u16 f2bf(float f) {
  union { float f; unsigned u; } v; v.f = f;
  unsigned r = v.u + 0x7FFFu + ((v.u >> 16) & 1u);   // RNE
  return (u16)(r >> 16);
}

__device__ __forceinline__ float tanh_fast(float x) {
  float cx = fminf(10.f, fmaxf(-10.f, x));
  float e = __expf(2.f * cx);
  return (e - 1.f) / (e + 1.f);
}

__global__ __launch_bounds__(256) void zero_flags_kernel(int* __restrict__ f) {
  f[blockIdx.x * 256 + threadIdx.x] = 0;
}

// x [256b][512t][256k] fp32 -> xpack bf16 frags [g][t][c(8)][lane(64)][j(8)]
__global__ __launch_bounds__(256) void pack_x_kernel(const float* __restrict__ x, u16* __restrict__ xpack) {
  const int l = threadIdx.x & 63;
  const int rib = threadIdx.x >> 6;
  const long bt = (long)blockIdx.x * 4 + rib;   // b*512 + t
  const int b = (int)(bt >> 9);
  const int t = (int)(bt & 511);
  const f32x4 xv = *(const f32x4*)(x + bt * 256 + l * 4);
  const int k = l * 4;
  const int g = b >> 4;
  const int c = k >> 5;
  const int lt = ((k >> 3) & 3) * 16 + (b & 15);
  const int j = k & 7;
  u16x4 o;
  o[0] = f2bf(xv[0]); o[1] = f2bf(xv[1]); o[2] = f2bf(xv[2]); o[3] = f2bf(xv[3]);
  const long idx = ((((long)g * 512 + t) * 8 + c) * 64 + lt) * 8 + j;
  *(u16x4*)(xpack + idx) = o;
}

// W_hh[1024][1024], W_hx[1024][256] -> wpack frags [(s*4+w)*10+kc][nt][lane][8]
// W_ho[128][1024] -> whop frags [nt*32+c][lane][8]
__global__ __launch_bounds__(256) void pack_w_kernel(const float* __restrict__ Whh, const float* __restrict__ Whx,
                                                     const float* __restrict__ Who, u16* __restrict__ wpack,
                                                     u16* __restrict__ whop) {
  const int fid = blockIdx.x * 256 + threadIdx.x;
  const int l = fid & 63;
  const int frag = fid >> 6;
  const float* src;
  u16* dst;
  if (frag < 2560) {
    const int nt = frag & 3;
    const int kc = (frag >> 2) % 10;
    const int sw = frag / 40;          // s*4 + w
    const int w = sw & 3, s = sw >> 2;
    const int n = s * 64 + nt * 16 + (l & 15);
    if (kc < 8) src = Whh + n * 1024 + 32 * (8 * w + kc) + 8 * (l >> 4);
    else        src = Whx + n * 256  + 32 * (2 * w + kc - 8) + 8 * (l >> 4);
    dst = wpack + ((long)frag * 64 + l) * 8;
  } else if (frag < 2816) {
    const int f2 = frag - 2560;
    const int c = f2 & 31, nt = f2 >> 5;
    const int o = nt * 16 + (l & 15);
    src = Who + o * 1024 + 32 * c + 8 * (l >> 4);
    dst = whop + ((long)f2 * 64 + l) * 8;
  } else {
    return;
  }
  const f32x4 a = *(const f32x4*)src;
  const f32x4 b = *(const f32x4*)(src + 4);
  u16x4 o0, o1;
  o0[0] = f2bf(a[0]); o0[1] = f2bf(a[1]); o0[2] = f2bf(a[2]); o0[3] = f2bf(a[3]);
  o1[0] = f2bf(b[0]); o1[1] = f2bf(b[1]); o1[2] = f2bf(b[2]); o1[3] = f2bf(b[3]);
  *(u16x4*)dst = o0;
  *(u16x4*)(dst + 4) = o1;
}

extern "C" __global__ __launch_bounds__(256, 1) void rnn_main(
    const short8* __restrict__ xpack, const short8* __restrict__ wpack,
    const short8* __restrict__ whop, const float* __restrict__ bhx,
    const float* __restrict__ bho, u16* __restrict__ hglob,
    int* __restrict__ flags, float* __restrict__ out) {
  __shared__ f32x4 red_lds[2][16 * 64];  // 32KB, double-buffered -> 1 barrier/step
  extern __shared__ f32x4 red2[];        // dynamic pad (occupancy) + final scratch

  const int tid = threadIdx.x;
  const int w = tid >> 6;              // wave id = K-slice id = owned out-tile id
  const int l = tid & 63;
  const int lr = l & 15, lgp = l >> 4;
  const int bid = blockIdx.x;
  const int g = bid & 15;              // cluster (batch group)
  const int s = bid >> 4;              // 64-out slice within cluster

  // --- load W' fragments into registers, once (40 x short8 = 160 regs/lane) ---
  short8 wreg[10][4];
  {
    const short8* wp = wpack + (long)(s * 4 + w) * 10 * 4 * 64;
#pragma unroll
    for (int kc = 0; kc < 10; kc++)
#pragma unroll
      for (int nt = 0; nt < 4; nt++)
        wreg[kc][nt] = wp[(kc * 4 + nt) * 64 + l];
  }
  const float bias = bhx[s * 64 + w * 16 + lr];
  const int n = s * 64 + w * 16 + lr;            // out index this lane stores
  const int cst = n >> 5, ltb = ((n >> 3) & 3) * 16, jst = n & 7;

  // --- xa software pipeline: preload step-0 fragments ---
  short8 nxa0, nxa1;
  {
    const short8* xp0 = xpack + (long)(g * 512 + 0) * 8 * 64;
    nxa0 = xp0[(2 * w + 0) * 64 + l];
    nxa1 = xp0[(2 * w + 1) * 64 + l];
  }

#pragma unroll 1
  for (int t = 0; t < 512; ++t) {
    // current step's x-frags come from the pipeline registers
    short8 xa0 = nxa0, xa1 = nxa1;
    // issue prefetch for t+1 NOW; its HBM latency hides under poll+h-load+MFMA
    {
      const int tn = (t + 1) & 511;
      const short8* xpn = xpack + (long)(g * 512 + tn) * 8 * 64;
      nxa0 = xpn[(2 * w + 0) * 64 + l];
      nxa1 = xpn[(2 * w + 1) * 64 + l];
    }

    f32x4 acc0 = {0.f, 0.f, 0.f, 0.f};
    f32x4 acc1 = acc0, acc2 = acc0, acc3 = acc0;

    MF(xa0, wreg[8][0], acc0); MF(xa0, wreg[8][1], acc1);
    MF(xa0, wreg[8][2], acc2); MF(xa0, wreg[8][3], acc3);
    MF(xa1, wreg[9][0], acc0); MF(xa1, wreg[9][1], acc1);
    MF(xa1, wreg[9][2], acc2); MF(xa1, wreg[9][3], acc3);

    if (t > 0) {
      // wait until all 64 waves of this cluster have published h_t
      const int* fp = flags + (size_t)((t - 1) * 16 + g) * 32;
      int v = ALOAD(fp);
      while (v < 64) {
        __builtin_amdgcn_s_sleep(1);
        v = ALOAD(fp);
      }
      // unbreakable dependency: h loads can't be hoisted above the poll
      unsigned dep = 0;
      asm volatile("" : "+v"(dep) : "v"(v));
      const u64* hq = (const u64*)(hglob + (size_t)(g * 2 + (t & 1)) * 16384) + dep;
      short8 ha[8];
#pragma unroll
      for (int i = 0; i < 8; i++) {
        union { u64 q[2]; short8 v8; } hu;
        const size_t qi = ((size_t)(w * 8 + i) * 64 + l) * 2;
        hu.q[0] = ALOAD(hq + qi + 0);
        hu.q[1] = ALOAD(hq + qi + 1);
        ha[i] = hu.v8;
      }
#pragma unroll
      for (int i = 0; i < 8; i++) {
        MF(ha[i], wreg[i][0], acc0);
        MF(ha[i], wreg[i][1], acc1);
        MF(ha[i], wreg[i][2], acc2);
        MF(ha[i], wreg[i][3], acc3);
      }
    }

    // cross-wave reduction of K-partials (double-buffered LDS, single barrier)
    f32x4* red = red_lds[t & 1];
    red[(w * 4 + 0) * 64 + l] = acc0;
    red[(w * 4 + 1) * 64 + l] = acc1;
    red[(w * 4 + 2) * 64 + l] = acc2;
    red[(w * 4 + 3) * 64 + l] = acc3;
    __syncthreads();
    f32x4 ssum = red[(0 + w) * 64 + l] + red[(4 + w) * 64 + l] +
                 red[(8 + w) * 64 + l] + red[(12 + w) * 64 + l];

    // epilogue: bias + tanh, publish h_{t+1} (cache-bypass stores, MALL-coherent)
    u16* dst = hglob + (size_t)(g * 2 + ((t + 1) & 1)) * 16384;
#pragma unroll
    for (int r = 0; r < 4; r++) {
      float hv = tanh_fast(ssum[r] + bias);
      ASTORE(dst + (size_t)(cst * 64 + ltb + 4 * lgp + r) * 8 + jst, f2bf(hv));
    }
    // per-wave drain + per-wave flag (count to 64); no block barrier needed —
    // each wave's 4 stores are its own outs, red_lds is double-buffered.
    asm volatile("s_waitcnt vmcnt(0)" ::: "memory");
    if (l == 0)
      __hip_atomic_fetch_add(flags + (size_t)(t * 16 + g) * 32, 1,
                             __ATOMIC_RELAXED, __HIP_MEMORY_SCOPE_AGENT);
  }

  // ---- final: logits + softmax, one block (s==0) per cluster ----
  if (s != 0) return;
  {
    const int* fp = flags + (size_t)(511 * 16 + g) * 32;
    int v = ALOAD(fp);
    while (v < 64) {
      __builtin_amdgcn_s_sleep(1);
      v = ALOAD(fp);
    }
    unsigned dep = 0;
    asm volatile("" : "+v"(dep) : "v"(v));
    const u64* hq = (const u64*)(hglob + (size_t)(g * 2 + 0) * 16384) + dep;  // h_512 in buf 0
    f32x4 oa[8] = {};
#pragma unroll
    for (int i = 0; i < 8; i++) {
      union { u64 q[2]; short8 v8; } hu;
      const size_t qi = ((size_t)(w * 8 + i) * 64 + l) * 2;
      hu.q[0] = ALOAD(hq + qi + 0);
      hu.q[1] = ALOAD(hq + qi + 1);
      short8 ha = hu.v8;
#pragma unroll
      for (int nt = 0; nt < 8; nt++)
        MF(ha, whop[(nt * 32 + w * 8 + i) * 64 + l], oa[nt]);
    }
#pragma unroll
    for (int nt = 0; nt < 8; nt++) red2[(w * 8 + nt) * 64 + l] = oa[nt];
  }
  __syncthreads();
#pragma unroll
  for (int qd = 0; qd < 2; qd++) {
    const int nt = 2 * w + qd;
    f32x4 lq = red2[(0 + nt) * 64 + l] + red2[(8 + nt) * 64 + l] +
               red2[(16 + nt) * 64 + l] + red2[(24 + nt) * 64 + l];
    const float bo = bho[nt * 16 + lr];
    lq[0] += bo; lq[1] += bo; lq[2] += bo; lq[3] += bo;
    red_lds[0][nt * 64 + l] = lq;
  }
  __syncthreads();
  if (w == 0) {
    const int b = l >> 2, qd = l & 3;  // 16 rows x 4 lane-groups (32 cols each)
    const float* redf = (const float*)red_lds[0];
    float vv[32];
    float mx = -3.0e38f;
#pragma unroll
    for (int jj = 0; jj < 32; jj++) {
      const int o = qd * 32 + jj;
      const int nt = o >> 4, m = o & 15;
      const float lv = redf[(nt * 64 + (b >> 2) * 16 + m) * 4 + (b & 3)];
      vv[jj] = lv;
      mx = fmaxf(mx, lv);
    }
    mx = fmaxf(mx, __shfl_xor(mx, 1));
    mx = fmaxf(mx, __shfl_xor(mx, 2));
    float se = 0.f;
#pragma unroll
    for (int jj = 0; jj < 32; jj++) { float e = __expf(vv[jj] - mx); vv[jj] = e; se += e; }
    se += __shfl_xor(se, 1);
    se += __shfl_xor(se, 2);
    const float inv = 1.f / se;
#pragma unroll
    for (int jj = 0; jj < 32; jj++)
      out[(g * 16 + b) * 128 + qd * 32 + jj] = vv[jj] * inv;
  }
}

extern "C" void kernel_launch(void* const* d_in, const int* in_sizes, int n_in,
                              void* d_out, int out_size, void* d_ws, size_t ws_size,
                              hipStream_t stream) {
  const float* x   = (const float*)d_in[0];
  const float* Whx = (const float*)d_in[1];
  const float* bhx = (const float*)d_in[2];
  const float* Whh = (const float*)d_in[3];
  const float* Who = (const float*)d_in[4];
  const float* bho = (const float*)d_in[5];
  float* out = (float*)d_out;
  char* ws = (char*)d_ws;

  u16* xpack = (u16*)(ws + XPACK_OFF);
  u16* wpack = (u16*)(ws + WPACK_OFF);
  u16* whop  = (u16*)(ws + WHOP_OFF);
  u16* hglob = (u16*)(ws + HGLOB_OFF);
  int* flags = (int*)(ws + FLAGS_OFF);

  zero_flags_kernel<<<1024, 256, 0, stream>>>(flags);
  pack_x_kernel<<<32768, 256, 0, stream>>>(x, xpack);
  pack_w_kernel<<<704, 256, 0, stream>>>(Whh, Whx, Who, wpack, whop);

  // LDS: static 32KB + dynamic 56KB = 88KB -> exactly 1 block/CU (spin-sync safe,
  // 256 blocks on 256 CUs). Fallback keeps all blocks resident (2/CU possible).
  size_t dynsz = 57344;
  if (hipFuncSetAttribute((const void*)rnn_main,
                          hipFuncAttributeMaxDynamicSharedMemorySize, 57344) != hipSuccess)
    dynsz = 32768;

  rnn_main<<<256, 256, dynsz, stream>>>((const short8*)xpack, (const short8*)wpack,
                                        (const short8*)whop, bhx, bho, hglob, flags, out);
}

// Round 7
// 1554.699 us; speedup vs baseline: 1.9090x; 1.2648x over previous
//
#include <hip/hip_runtime.h>

// VanillaRNN on MI355X — round 7: r3 skeleton (proven), minus fat.
//  * sub-flags per block-quad (4-way RMW fan-in, one 128B line each); consumer
//    wave w polls only ITS producers' sub-flag -> partial-order sync
//  * one barrier/step: red dbuf + per-wave vmcnt(0) drain + LDS arrival counter,
//    last wave does the single global fetch_add
//  * 2-deep pipelined poll (inline asm, counted vmcnt) -> detect ~RT/2 sooner
// All cross-block data/sync via MALL-coherent relaxed agent atomics (sc0 sc1).
// No agent fences in the loop; no XCD/L2 assumptions (r6 deadlock lesson).

typedef __attribute__((ext_vector_type(8))) short short8;
typedef __attribute__((ext_vector_type(4))) float f32x4;
typedef __attribute__((ext_vector_type(4))) unsigned short u16x4;
typedef unsigned short u16;
typedef unsigned int u32;
typedef unsigned long long u64;

#define MF(A, B, C) (C) = __builtin_amdgcn_mfma_f32_16x16x32_bf16((A), (B), (C), 0, 0, 0)
#define ALOAD(p)    __hip_atomic_load((p), __ATOMIC_RELAXED, __HIP_MEMORY_SCOPE_AGENT)
#define ASTORE(p,v) __hip_atomic_store((p), (v), __ATOMIC_RELAXED, __HIP_MEMORY_SCOPE_AGENT)

// ---- workspace layout (bytes) ----
#define XPACK_OFF   0UL           // 16g * 512t * 8192B          = 67108864
#define WPACK_OFF   67108864UL    // 2560 frags * 1024B          = 2621440
#define WHOP_OFF    69730304UL    // 256 frags * 1024B           = 262144
#define HGLOB_OFF   69992448UL    // 16g * 2buf * 32KB           = 1048576
#define FLAGS_OFF   71041024UL    // 512t * 16g * 4q * 128B      = 4194304
// total 75235328 bytes

__device__ __forceinline__ u16 f2bf(float f) {
  union { float f; unsigned u; } v; v.f = f;
  unsigned r = v.u + 0x7FFFu + ((v.u >> 16) & 1u);   // RNE
  return (u16)(r >> 16);
}

__device__ __forceinline__ float tanh_fast(float x) {
  float cx = fminf(10.f, fmaxf(-10.f, x));
  float e = __expf(2.f * cx);
  return (e - 1.f) / (e + 1.f);
}

__global__ __launch_bounds__(256) void zero_flags_kernel(int* __restrict__ f) {
  f[(size_t)blockIdx.x * 256 + threadIdx.x] = 0;
}

// x [256b][512t][256k] fp32 -> xpack bf16 frags [g][t][c(8)][lane(64)][j(8)]
__global__ __launch_bounds__(256) void pack_x_kernel(const float* __restrict__ x, u16* __restrict__ xpack) {
  const int l = threadIdx.x & 63;
  const int rib = threadIdx.x >> 6;
  const long bt = (long)blockIdx.x * 4 + rib;   // b*512 + t
  const int b = (int)(bt >> 9);
  const int t = (int)(bt & 511);
  const f32x4 xv = *(const f32x4*)(x + bt * 256 + l * 4);
  const int k = l * 4;
  const int g = b >> 4;
  const int c = k >> 5;
  const int lt = ((k >> 3) & 3) * 16 + (b & 15);
  const int j = k & 7;
  u16x4 o;
  o[0] = f2bf(xv[0]); o[1] = f2bf(xv[1]); o[2] = f2bf(xv[2]); o[3] = f2bf(xv[3]);
  const long idx = ((((long)g * 512 + t) * 8 + c) * 64 + lt) * 8 + j;
  *(u16x4*)(xpack + idx) = o;
}

// W_hh[1024][1024], W_hx[1024][256] -> wpack frags [(s*4+w)*10+kc][nt][lane][8]
// W_ho[128][1024] -> whop frags [nt*32+c][lane][8]
__global__ __launch_bounds__(256) void pack_w_kernel(const float* __restrict__ Whh, const float* __restrict__ Whx,
                                                     const float* __restrict__ Who, u16* __restrict__ wpack,
                                                     u16* __restrict__ whop) {
  const int fid = blockIdx.x * 256 + threadIdx.x;
  const int l = fid & 63;
  const int frag = fid >> 6;
  const float* src;
  u16* dst;
  if (frag < 2560) {
    const int nt = frag & 3;
    const int kc = (frag >> 2) % 10;
    const int sw = frag / 40;          // s*4 + w
    const int w = sw & 3, s = sw >> 2;
    const int n = s * 64 + nt * 16 + (l & 15);
    if (kc < 8) src = Whh + n * 1024 + 32 * (8 * w + kc) + 8 * (l >> 4);
    else        src = Whx + n * 256  + 32 * (2 * w + kc - 8) + 8 * (l >> 4);
    dst = wpack + ((long)frag * 64 + l) * 8;
  } else if (frag < 2816) {
    const int f2 = frag - 2560;
    const int c = f2 & 31, nt = f2 >> 5;
    const int o = nt * 16 + (l & 15);
    src = Who + o * 1024 + 32 * c + 8 * (l >> 4);
    dst = whop + ((long)f2 * 64 + l) * 8;
  } else {
    return;
  }
  const f32x4 a = *(const f32x4*)src;
  const f32x4 b = *(const f32x4*)(src + 4);
  u16x4 o0, o1;
  o0[0] = f2bf(a[0]); o0[1] = f2bf(a[1]); o0[2] = f2bf(a[2]); o0[3] = f2bf(a[3]);
  o1[0] = f2bf(b[0]); o1[1] = f2bf(b[1]); o1[2] = f2bf(b[2]); o1[3] = f2bf(b[3]);
  *(u16x4*)dst = o0;
  *(u16x4*)(dst + 4) = o1;
}

// 2-deep pipelined poll of one flag dword (wave-uniform address).
// FIFO vmcnt semantics (m135): vmcnt(1) waits the OLDER of 2 outstanding loads.
// Exits with vmcnt(0) drained (no stray loads leak into caller's counts).
__device__ __forceinline__ int pollflag(const int* fp, int target) {
  int a, b;
  asm volatile(
    "global_load_dword %0, %2, off sc0 sc1\n\t"
    "global_load_dword %1, %2, off sc0 sc1\n\t"
    "1:\n\t"
    "s_waitcnt vmcnt(1)\n\t"
    "v_cmp_ge_i32 vcc, %0, %3\n\t"
    "s_cbranch_vccnz 2f\n\t"
    "global_load_dword %0, %2, off sc0 sc1\n\t"
    "s_waitcnt vmcnt(1)\n\t"
    "v_cmp_ge_i32 vcc, %1, %3\n\t"
    "s_cbranch_vccnz 2f\n\t"
    "global_load_dword %1, %2, off sc0 sc1\n\t"
    "s_branch 1b\n\t"
    "2:\n\t"
    "s_waitcnt vmcnt(0)"
    : "=&v"(a), "=&v"(b)
    : "v"(fp), "v"(target)
    : "vcc", "memory");
  return a;   // data-dependent on a poll load (monotone flag -> valid)
}

extern "C" __global__ __launch_bounds__(256, 1) void rnn_main(
    const short8* __restrict__ xpack, const short8* __restrict__ wpack,
    const short8* __restrict__ whop, const float* __restrict__ bhx,
    const float* __restrict__ bho, u16* __restrict__ hglob,
    int* __restrict__ flags, float* __restrict__ out) {
  __shared__ f32x4 red_lds[2][1024];   // 32KB, double-buffered -> 1 barrier/step
  __shared__ int cnt_lds[512];         // per-step wave-arrival counter
  extern __shared__ f32x4 pad_lds[];   // occupancy pad only (final reuses red_lds)

  const int tid = threadIdx.x;
  const int w = tid >> 6;              // wave id = K-slice id
  const int l = tid & 63;
  const int lr = l & 15, lgp = l >> 4;
  const int bid = blockIdx.x;
  const int g = bid & 15;              // cluster (batch group)
  const int s = bid >> 4;              // 64-out slice within cluster

  cnt_lds[tid] = 0; cnt_lds[tid + 256] = 0;
  (void)pad_lds;

  // --- load W' fragments into registers, once (40 x short8 = 160 regs/lane) ---
  short8 wreg[10][4];
  {
    const short8* wp = wpack + (long)(s * 4 + w) * 40 * 64;
#pragma unroll
    for (int kc = 0; kc < 10; kc++)
#pragma unroll
      for (int nt = 0; nt < 4; nt++)
        wreg[kc][nt] = wp[(kc * 4 + nt) * 64 + l];
  }
  const float bias = bhx[s * 64 + w * 16 + lr];
  const int n = s * 64 + w * 16 + lr;            // out index this lane stores
  const int cst = n >> 5, ltb = ((n >> 3) & 3) * 16, jst = n & 7;
  __syncthreads();                                // cnt_lds zeroed

#pragma unroll 1
  for (int t = 0; t < 512; ++t) {
    // x-part A-frags (plain cached loads, read-only; usually L2-hit via siblings)
    const short8* xp = xpack + (long)(g * 512 + t) * 8 * 64;
    short8 xa0 = xp[(2 * w + 0) * 64 + l];
    short8 xa1 = xp[(2 * w + 1) * 64 + l];

    f32x4 acc0 = {0.f, 0.f, 0.f, 0.f};
    f32x4 acc1 = acc0, acc2 = acc0, acc3 = acc0;

    MF(xa0, wreg[8][0], acc0); MF(xa0, wreg[8][1], acc1);
    MF(xa0, wreg[8][2], acc2); MF(xa0, wreg[8][3], acc3);
    MF(xa1, wreg[9][0], acc0); MF(xa1, wreg[9][1], acc1);
    MF(xa1, wreg[9][2], acc2); MF(xa1, wreg[9][3], acc3);

    if (t > 0) {
      // make poll's vmcnt arithmetic exact: nothing outstanding at entry
      asm volatile("s_waitcnt vmcnt(0)" ::: "memory");
      // wave w needs h chunks from producer blocks 4w..4w+3 only -> sub-flag w
      const int* fq = flags + (((size_t)(t - 1) * 16 + g) * 4 + w) * 32;
      int v = pollflag(fq, 4);
      unsigned dep = 0;
      asm volatile("" : "+v"(dep) : "v"(v));   // unbreakable edge: h after poll
      const u64* hq = (const u64*)(hglob + (size_t)(g * 2 + (t & 1)) * 16384) + dep;
      short8 ha[8];
#pragma unroll
      for (int i = 0; i < 8; i++) {
        union { u64 q[2]; short8 v8; } hu;
        const size_t qi = ((size_t)(w * 8 + i) * 64 + l) * 2;
        hu.q[0] = ALOAD(hq + qi + 0);
        hu.q[1] = ALOAD(hq + qi + 1);
        ha[i] = hu.v8;
      }
#pragma unroll
      for (int i = 0; i < 8; i++) {
        MF(ha[i], wreg[i][0], acc0);
        MF(ha[i], wreg[i][1], acc1);
        MF(ha[i], wreg[i][2], acc2);
        MF(ha[i], wreg[i][3], acc3);
      }
    }

    // cross-wave reduction of K-partials (double-buffered LDS, single barrier)
    f32x4* red = red_lds[t & 1];
    red[(w * 4 + 0) * 64 + l] = acc0;
    red[(w * 4 + 1) * 64 + l] = acc1;
    red[(w * 4 + 2) * 64 + l] = acc2;
    red[(w * 4 + 3) * 64 + l] = acc3;
    __syncthreads();
    f32x4 ssum = red[(0 + w) * 64 + l] + red[(4 + w) * 64 + l] +
                 red[(8 + w) * 64 + l] + red[(12 + w) * 64 + l];

    // epilogue: bias + tanh, publish h_{t+1} (MALL-coherent stores)
    u16* dst = hglob + (size_t)(g * 2 + ((t + 1) & 1)) * 16384;
#pragma unroll
    for (int r = 0; r < 4; r++) {
      float hv = tanh_fast(ssum[r] + bias);
      ASTORE(dst + (size_t)(cst * 64 + ltb + 4 * lgp + r) * 8 + jst, f2bf(hv));
    }
    // per-wave drain, LDS arrival count; last wave bumps the block-quad sub-flag
    asm volatile("s_waitcnt vmcnt(0)" ::: "memory");
    if (l == 0) {
      int old = atomicAdd(&cnt_lds[t], 1);
      if (old == 3)
        __hip_atomic_fetch_add(flags + (((size_t)t * 16 + g) * 4 + (s >> 2)) * 32, 1,
                               __ATOMIC_RELAXED, __HIP_MEMORY_SCOPE_AGENT);
    }
  }

  // ---- final: logits + softmax, one block (s==0) per cluster ----
  if (s != 0) return;
  f32x4* red2 = &red_lds[0][0];   // alias: oa staging reuses the 32KB dbuf
  {
    asm volatile("s_waitcnt vmcnt(0)" ::: "memory");
    const int* fq = flags + (((size_t)511 * 16 + g) * 4 + w) * 32;
    int v = pollflag(fq, 4);
    unsigned dep = 0;
    asm volatile("" : "+v"(dep) : "v"(v));
    const u64* hq = (const u64*)(hglob + (size_t)(g * 2 + 0) * 16384) + dep;  // h_512
    f32x4 oa[8] = {};
#pragma unroll
    for (int i = 0; i < 8; i++) {
      union { u64 q[2]; short8 v8; } hu;
      const size_t qi = ((size_t)(w * 8 + i) * 64 + l) * 2;
      hu.q[0] = ALOAD(hq + qi + 0);
      hu.q[1] = ALOAD(hq + qi + 1);
      short8 ha = hu.v8;
#pragma unroll
      for (int nt = 0; nt < 8; nt++)
        MF(ha, whop[(nt * 32 + w * 8 + i) * 64 + l], oa[nt]);
    }
    __syncthreads();   // everyone past loop-phase red_lds use before alias write
#pragma unroll
    for (int nt = 0; nt < 8; nt++) red2[(w * 8 + nt) * 64 + l] = oa[nt];
  }
  __syncthreads();
#pragma unroll
  for (int qd = 0; qd < 2; qd++) {
    const int nt = 2 * w + qd;
    // each [nt*64+l] slot is read only by the thread that rewrites it below
    f32x4 lq = red2[(0 + nt) * 64 + l] + red2[(8 + nt) * 64 + l] +
               red2[(16 + nt) * 64 + l] + red2[(24 + nt) * 64 + l];
    const float bo = bho[nt * 16 + lr];
    lq[0] += bo; lq[1] += bo; lq[2] += bo; lq[3] += bo;
    red_lds[0][nt * 64 + l] = lq;
  }
  __syncthreads();
  if (w == 0) {
    const int b = l >> 2, qd = l & 3;  // 16 rows x 4 lane-groups (32 cols each)
    const float* redf = (const float*)red_lds[0];
    float vv[32];
    float mx = -3.0e38f;
#pragma unroll
    for (int jj = 0; jj < 32; jj++) {
      const int o = qd * 32 + jj;
      const int nt = o >> 4, m = o & 15;
      const float lv = redf[(nt * 64 + (b >> 2) * 16 + m) * 4 + (b & 3)];
      vv[jj] = lv;
      mx = fmaxf(mx, lv);
    }
    mx = fmaxf(mx, __shfl_xor(mx, 1));
    mx = fmaxf(mx, __shfl_xor(mx, 2));
    float se = 0.f;
#pragma unroll
    for (int jj = 0; jj < 32; jj++) { float e = __expf(vv[jj] - mx); vv[jj] = e; se += e; }
    se += __shfl_xor(se, 1);
    se += __shfl_xor(se, 2);
    const float inv = 1.f / se;
#pragma unroll
    for (int jj = 0; jj < 32; jj++)
      out[(g * 16 + b) * 128 + qd * 32 + jj] = vv[jj] * inv;
  }
}

extern "C" void kernel_launch(void* const* d_in, const int* in_sizes, int n_in,
                              void* d_out, int out_size, void* d_ws, size_t ws_size,
                              hipStream_t stream) {
  const float* x   = (const float*)d_in[0];
  const float* Whx = (const float*)d_in[1];
  const float* bhx = (const float*)d_in[2];
  const float* Whh = (const float*)d_in[3];
  const float* Who = (const float*)d_in[4];
  const float* bho = (const float*)d_in[5];
  float* out = (float*)d_out;
  char* ws = (char*)d_ws;

  u16* xpack = (u16*)(ws + XPACK_OFF);
  u16* wpack = (u16*)(ws + WPACK_OFF);
  u16* whop  = (u16*)(ws + WHOP_OFF);
  u16* hglob = (u16*)(ws + HGLOB_OFF);
  int* flags = (int*)(ws + FLAGS_OFF);

  zero_flags_kernel<<<4096, 256, 0, stream>>>(flags);   // 4MB sub-flags -> 0
  pack_x_kernel<<<32768, 256, 0, stream>>>(x, xpack);
  pack_w_kernel<<<704, 256, 0, stream>>>(Whh, Whx, Who, wpack, whop);

  // LDS: static ~34.3KB + dynamic 48KB > 80KB -> exactly 1 block/CU (256 blocks
  // on 256 CUs, all resident -> spin-sync safe). Fallback 28KB -> <=2/CU, still
  // all resident (128 CUs suffice).
  size_t dynsz = 49152;
  if (hipFuncSetAttribute((const void*)rnn_main,
                          hipFuncAttributeMaxDynamicSharedMemorySize, 49152) != hipSuccess)
    dynsz = 28672;

  rnn_main<<<256, 256, dynsz, stream>>>((const short8*)xpack, (const short8*)wpack,
                                        (const short8*)whop, bhx, bho, hglob, flags, out);
}